// Round 1
// baseline (381.012 us; speedup 1.0000x reference)
//
#include <hip/hip_runtime.h>

// DistillingLoss: mean over batch of sum_j(-target_ij * log(input_ij))
// B=8192, C=32000, fp32 in, scalar fp32 out.
// Memory-bound streaming reduction: 2.097 GB read -> ~333 us at 6.3 TB/s.

#define DL_BATCH 8192
#define DL_CLASSES 32000

// Pass 1: grid-stride float4 reduction, one fp32 partial per block.
__global__ __launch_bounds__(256) void dl_partial_kernel(
    const float4* __restrict__ inp,
    const float4* __restrict__ tgt,
    float* __restrict__ partials,
    long n4)
{
    long idx    = (long)blockIdx.x * blockDim.x + threadIdx.x;
    long stride = (long)gridDim.x * blockDim.x;

    float acc = 0.0f;
    for (long i = idx; i < n4; i += stride) {
        float4 x = inp[i];
        float4 t = tgt[i];
        // -t * log(x); __logf -> v_log_f32 (log2) * ln2, plenty accurate for
        // x in [0.01, 1] vs the ~2% tolerance.
        acc = fmaf(-t.x, __logf(x.x), acc);
        acc = fmaf(-t.y, __logf(x.y), acc);
        acc = fmaf(-t.z, __logf(x.z), acc);
        acc = fmaf(-t.w, __logf(x.w), acc);
    }

    // wave-64 butterfly-free down-reduce
    #pragma unroll
    for (int off = 32; off > 0; off >>= 1)
        acc += __shfl_down(acc, off, 64);

    __shared__ float wave_sums[4];  // 256 threads = 4 waves
    const int wave = threadIdx.x >> 6;
    const int lane = threadIdx.x & 63;
    if (lane == 0) wave_sums[wave] = acc;
    __syncthreads();

    if (threadIdx.x == 0) {
        partials[blockIdx.x] =
            wave_sums[0] + wave_sums[1] + wave_sums[2] + wave_sums[3];
    }
}

// Pass 2: single block, double accumulation of the block partials,
// divide by BATCH. Deterministic (no atomics).
__global__ __launch_bounds__(256) void dl_final_kernel(
    const float* __restrict__ partials,
    int n,
    float* __restrict__ out)
{
    double acc = 0.0;
    for (int i = threadIdx.x; i < n; i += blockDim.x)
        acc += (double)partials[i];

    #pragma unroll
    for (int off = 32; off > 0; off >>= 1)
        acc += __shfl_down(acc, off, 64);

    __shared__ double wave_sums[4];
    const int wave = threadIdx.x >> 6;
    const int lane = threadIdx.x & 63;
    if (lane == 0) wave_sums[wave] = acc;
    __syncthreads();

    if (threadIdx.x == 0) {
        double total = wave_sums[0] + wave_sums[1] + wave_sums[2] + wave_sums[3];
        out[0] = (float)(total / (double)DL_BATCH);
    }
}

extern "C" void kernel_launch(void* const* d_in, const int* in_sizes, int n_in,
                              void* d_out, int out_size, void* d_ws, size_t ws_size,
                              hipStream_t stream) {
    const float4* inp = (const float4*)d_in[0];
    const float4* tgt = (const float4*)d_in[1];
    float* out = (float*)d_out;
    float* partials = (float*)d_ws;

    const long n_elems = (long)DL_BATCH * (long)DL_CLASSES;  // 262,144,000
    const long n4 = n_elems / 4;                             // divisible by 4

    const int block = 256;
    const int grid = 2048;  // 256 CUs x 8 blocks, grid-stride covers the rest

    dl_partial_kernel<<<grid, block, 0, stream>>>(inp, tgt, partials, n4);
    dl_final_kernel<<<1, block, 0, stream>>>(partials, grid, out);
}